// Round 7
// baseline (497.786 us; speedup 1.0000x reference)
//
#include <hip/hip_runtime.h>
#include <hip/hip_bf16.h>

// MultiHeadAttention: B=2, S=2048, H=16, d=64, D=1024. I/O fp32; compute bf16 MFMA.
// [cvt] fp32->bf16 -> [qkv] X@W^T+b (Q pre-scaled by 0.125*log2e; K row-major;
// V as [B,H,64,2048]) -> [attn] wave-private flash attention, fixed-max softmax,
// K/V fragments read DIRECTLY from global (L2-resident; no LDS staging; only the
// P C->A layout round-trip uses LDS) -> [proj] O@Wo^T+bo -> fp32 d_out.

typedef unsigned short u16;
typedef __attribute__((ext_vector_type(8))) short short8;   // 8 bf16 (MFMA A/B frag)
typedef __attribute__((ext_vector_type(4))) float floatx4;  // MFMA C/D frag

__device__ __forceinline__ float bf2f(u16 x) {
  return __uint_as_float(((unsigned)x) << 16);
}
__device__ __forceinline__ u16 f2bf(float f) {
  unsigned x = __float_as_uint(f);
  return (u16)((x + 0x7fffu + ((x >> 16) & 1u)) >> 16);  // RNE
}
__device__ __forceinline__ ushort2 pk_bf16(float a, float b) {
  __hip_bfloat162 h2 = __float22bfloat162_rn(make_float2(a, b));  // HW packed cvt
  ushort2 u;
  __builtin_memcpy(&u, &h2, 4);
  return u;
}
#if __has_builtin(__builtin_amdgcn_exp2f)
#define EXP2(x) __builtin_amdgcn_exp2f(x)
#else
#define EXP2(x) exp2f(x)
#endif
__device__ __forceinline__ void gll16(const u16* g, u16* lds) {
  __builtin_amdgcn_global_load_lds((const __attribute__((address_space(1))) void*)g,
                                   (__attribute__((address_space(3))) void*)lds,
                                   16, 0, 0);
}
// Compiler reorder barrier + DS drain (doesn't touch vmcnt: global loads in flight)
#define DSFENCE() __asm__ volatile("s_waitcnt lgkmcnt(0)" ::: "memory")

// ---------------------------------------------------------------------------
// fp32 -> bf16 of all 11 inputs. 16388 blocks x 256 thr x 4 elem, exact cover.
// ---------------------------------------------------------------------------
__global__ __launch_bounds__(256) void cvt_kernel(
    const float* __restrict__ q, const float* __restrict__ k, const float* __restrict__ v,
    const float* __restrict__ wq, const float* __restrict__ wk,
    const float* __restrict__ wv, const float* __restrict__ wo,
    const float* __restrict__ bq, const float* __restrict__ bk,
    const float* __restrict__ bv, const float* __restrict__ bo,
    u16* __restrict__ ws) {
  const int i4 = (blockIdx.x * 256 + threadIdx.x) * 4;
  const float* src;
  u16* dst;
  int local;
  if (i4 < 4194304)        { src = q;  dst = ws;            local = i4; }
  else if (i4 < 8388608)   { src = k;  dst = ws + 4194304;  local = i4 - 4194304; }
  else if (i4 < 12582912)  { src = v;  dst = ws + 8388608;  local = i4 - 8388608; }
  else if (i4 < 13631488)  { src = wq; dst = ws + 12582912; local = i4 - 12582912; }
  else if (i4 < 14680064)  { src = wk; dst = ws + 13631488; local = i4 - 13631488; }
  else if (i4 < 15728640)  { src = wv; dst = ws + 14680064; local = i4 - 14680064; }
  else if (i4 < 16777216)  { src = wo; dst = ws + 15728640; local = i4 - 15728640; }
  else if (i4 < 16778240)  { src = bq; dst = ws + 16777216; local = i4 - 16777216; }
  else if (i4 < 16779264)  { src = bk; dst = ws + 16779264; local = i4 - 16778240; }
  else if (i4 < 16780288)  { src = bv; dst = ws + 16781312; local = i4 - 16779264; }
  else                     { src = bo; dst = ws + 16783360; local = i4 - 16780288; }
  const float4 f = *(const float4*)(src + local);
  ushort4 o;
  o.x = f2bf(f.x); o.y = f2bf(f.y); o.z = f2bf(f.z); o.w = f2bf(f.w);
  *(ushort4*)(dst + local) = o;
}

// ---------------------------------------------------------------------------
// GEMM tile (m97 structure): out[m][n] = (X[m][:].W[n][:] + bias[n]) * oscale
// 256 thr (2x2 waves of 64x64), tile 128x128, BK=32, gll16 width-16 staging.
// mode 0: bf16 row-major. mode 1: bf16 [b][h][dd][s]. mode 2: fp32 row-major.
// ---------------------------------------------------------------------------
__device__ __forceinline__ void gemm_tile(
    const u16* __restrict__ X, const u16* __restrict__ W,
    const u16* __restrict__ bias, u16* __restrict__ out16, float* __restrict__ out32,
    int row0, int col0, int mode, float oscale, u16* As, u16* Bs) {
  const int tid = threadIdx.x;
  const int w = tid >> 6, l = tid & 63;
  const int lan = l & 15, quad = l >> 4;
  const int wm = w & 1, wn = w >> 1;

  floatx4 acc[4][4];
#pragma unroll
  for (int i = 0; i < 4; ++i)
#pragma unroll
    for (int j = 0; j < 4; ++j) acc[i][j] = (floatx4)0.0f;

  const int r0 = tid >> 2, kq0 = tid & 3;
  const int r1 = (tid + 256) >> 2;
  u16* aB0 = As + w * 512;
  u16* aB1 = As + 2048 + w * 512;
  u16* bB0 = Bs + w * 512;
  u16* bB1 = Bs + 2048 + w * 512;
  const u16* Xa0 = X + (size_t)(row0 + r0) * 1024 + kq0 * 8;
  const u16* Xa1 = X + (size_t)(row0 + r1) * 1024 + kq0 * 8;
  const u16* Wb0 = W + (size_t)(col0 + r0) * 1024 + kq0 * 8;
  const u16* Wb1 = W + (size_t)(col0 + r1) * 1024 + kq0 * 8;

  for (int kt = 0; kt < 32; ++kt) {
    gll16(Xa0 + kt * 32, aB0);
    gll16(Xa1 + kt * 32, aB1);
    gll16(Wb0 + kt * 32, bB0);
    gll16(Wb1 + kt * 32, bB1);
    __syncthreads();

    short8 af[4], bfr[4];
#pragma unroll
    for (int i = 0; i < 4; ++i)
      af[i] = *(const short8*)(As + (wm * 64 + i * 16 + lan) * 32 + quad * 8);
#pragma unroll
    for (int j = 0; j < 4; ++j)
      bfr[j] = *(const short8*)(Bs + (wn * 64 + j * 16 + lan) * 32 + quad * 8);
#pragma unroll
    for (int i = 0; i < 4; ++i)
#pragma unroll
      for (int j = 0; j < 4; ++j)
        acc[i][j] = __builtin_amdgcn_mfma_f32_16x16x32_bf16(af[i], bfr[j], acc[i][j], 0, 0, 0);
    __syncthreads();
  }

#pragma unroll
  for (int i = 0; i < 4; ++i) {
    const int mb = row0 + wm * 64 + i * 16 + quad * 4;
#pragma unroll
    for (int j = 0; j < 4; ++j) {
      const int n = col0 + wn * 64 + j * 16 + lan;
      const float bv = bf2f(bias[n]);
      if (mode == 0) {
#pragma unroll
        for (int r = 0; r < 4; ++r)
          out16[(size_t)(mb + r) * 1024 + n] = f2bf((acc[i][j][r] + bv) * oscale);
      } else if (mode == 1) {
        const int b = mb >> 11, s = mb & 2047;
        const int h = n >> 6, dd = n & 63;
        ushort4 v;
        v.x = f2bf(acc[i][j][0] + bv);
        v.y = f2bf(acc[i][j][1] + bv);
        v.z = f2bf(acc[i][j][2] + bv);
        v.w = f2bf(acc[i][j][3] + bv);
        *(ushort4*)(out16 + (size_t)((b * 16 + h) * 64 + dd) * 2048 + s) = v;
      } else {
#pragma unroll
        for (int r = 0; r < 4; ++r)
          out32[(size_t)(mb + r) * 1024 + n] = acc[i][j][r] + bv;
      }
    }
  }
}

__global__ __launch_bounds__(256) void qkv_kernel(
    const u16* __restrict__ xq, const u16* __restrict__ xk, const u16* __restrict__ xv,
    const u16* __restrict__ Wq, const u16* __restrict__ Wk, const u16* __restrict__ Wv,
    const u16* __restrict__ bq, const u16* __restrict__ bk, const u16* __restrict__ bv,
    u16* __restrict__ Qo, u16* __restrict__ Ko, u16* __restrict__ Vto) {
  __shared__ __align__(16) u16 As[128 * 32];
  __shared__ __align__(16) u16 Bs[128 * 32];
  const int bx = blockIdx.x;           // 0..767
  const int tile_m = bx / 24;
  const int rem = bx - tile_m * 24;
  const int which = rem >> 3;          // 0=Q 1=K 2=V
  const int col0 = (rem & 7) * 128;
  const u16* X = which == 0 ? xq : (which == 1 ? xk : xv);
  const u16* W = which == 0 ? Wq : (which == 1 ? Wk : Wv);
  const u16* bias = which == 0 ? bq : (which == 1 ? bk : bv);
  u16* out = which == 0 ? Qo : (which == 1 ? Ko : Vto);
  const float C = 0.125f * 1.4426950408889634f;  // fold scale*log2e into Q
  gemm_tile(X, W, bias, out, nullptr, tile_m * 128, col0, which == 2 ? 1 : 0,
            which == 0 ? C : 1.0f, As, Bs);
}

__global__ __launch_bounds__(256) void proj_kernel(
    const u16* __restrict__ X, const u16* __restrict__ W,
    const u16* __restrict__ bias, float* __restrict__ out) {
  __shared__ __align__(16) u16 As[128 * 32];
  __shared__ __align__(16) u16 Bs[128 * 32];
  const int bx = blockIdx.x;  // 0..255
  gemm_tile(X, W, bias, nullptr, out, (bx >> 3) * 128, (bx & 7) * 128, 2, 1.0f, As, Bs);
}

// ---------------------------------------------------------------------------
// Flash attention v5: wave-private key-split, ZERO-staging K-loop.
// Block = 64 q-rows of one (b,h); wave w owns keys [w*512,(w+1)*512) in 16 tiles
// of 32. Fixed-max softmax (p=exp2(C*qk-16); C folded into Q, -16 in sacc init)
// => partial O/l additive across waves; single end merge.
// Q/K/V MFMA fragments are loaded DIRECTLY from global:
//  - Q row-major: A-frag = 16B/lane, 16 rows x 64B contiguous segments (once).
//  - K row-major: B-frag = 16B/lane, 16 rows x 64B segments; tile reused by all
//    32 q-tile blocks of the same (b,h) -> L2-resident.
//  - Vt [b][h][dd][s]: already B-frag layout for PV.
// Only P does an LDS round-trip (C->A layout transform), wave-private, stride 40
// (80B rows: 16B-aligned, reads 2-way). NO barriers in the K-loop.
// LDS: Ps 4x2560 u16 = 20 KB + Lbuf 1 KB -> several blocks/CU; VGPR cap 168 (3/EU).
// ---------------------------------------------------------------------------
#define FIXMAX 16.0f
__global__ __launch_bounds__(256, 3) void attn_kernel(
    const u16* __restrict__ Q, const u16* __restrict__ K,
    const u16* __restrict__ Vt, u16* __restrict__ O) {
  __shared__ __align__(16) u16 Pslds[10240];  // [w][64 q][40]
  __shared__ float Lbuf[256];                 // [w][64 q] l partials
  const int tid = threadIdx.x;
  const int w = tid >> 6, l = tid & 63;
  const int lan = l & 15, quad = l >> 4;
  const int q0 = blockIdx.x * 64;
  const int bh = blockIdx.y;
  const int b = bh >> 4, h = bh & 15;
  const u16* Qg = Q + (size_t)(b * 2048 + q0) * 1024 + h * 64;
  const u16* Kg = K + (size_t)(b * 2048 + w * 512) * 1024 + h * 64;  // wave's keys
  const u16* Vg = Vt + (size_t)((b * 16 + h) * 64) * 2048 + w * 512;
  u16* Psw = Pslds + w * 2560;

  // Q -> registers: A-frag aq[mi][kk] = Q[q=mi*16+lan][dd=kk*32+quad*8 ..+8]
  short8 aq[4][2];
#pragma unroll
  for (int mi = 0; mi < 4; ++mi)
#pragma unroll
    for (int kk = 0; kk < 2; ++kk)
      aq[mi][kk] = *(const short8*)(Qg + (size_t)(mi * 16 + lan) * 1024 + kk * 32 + quad * 8);

  float lrun[4][4];
  floatx4 oacc[4][4];
#pragma unroll
  for (int mi = 0; mi < 4; ++mi) {
#pragma unroll
    for (int r = 0; r < 4; ++r) lrun[mi][r] = 0.f;
#pragma unroll
    for (int nd = 0; nd < 4; ++nd) oacc[mi][nd] = (floatx4)0.0f;
  }

  for (int kt = 0; kt < 16; ++kt) {
    // K B-frags direct from global: K[n=key][k=dd]; 16 rows x 64B segments
    short8 bkf[2][2];
#pragma unroll
    for (int nj = 0; nj < 2; ++nj)
#pragma unroll
      for (int kk = 0; kk < 2; ++kk)
        bkf[nj][kk] = *(const short8*)(Kg + (size_t)(kt * 32 + nj * 16 + lan) * 1024 +
                                       kk * 32 + quad * 8);
    // V B-frags direct from global (Vt layout IS the B-frag layout)
    short8 vb[4];
#pragma unroll
    for (int nd = 0; nd < 4; ++nd)
      vb[nd] = *(const short8*)(Vg + (size_t)(nd * 16 + lan) * 2048 + kt * 32 + quad * 8);

    // S = Q K^T : 64q x 32keys
    floatx4 sacc[4][2];
#pragma unroll
    for (int mi = 0; mi < 4; ++mi)
#pragma unroll
      for (int nj = 0; nj < 2; ++nj) sacc[mi][nj] = (floatx4)(-FIXMAX);
#pragma unroll
    for (int kk = 0; kk < 2; ++kk)
#pragma unroll
      for (int mi = 0; mi < 4; ++mi)
#pragma unroll
        for (int nj = 0; nj < 2; ++nj)
          sacc[mi][nj] =
              __builtin_amdgcn_mfma_f32_16x16x32_bf16(aq[mi][kk], bkf[nj][kk], sacc[mi][nj], 0, 0, 0);

    // fixed-max softmax; C/D: row=quad*4+r, col=lan per nj tile
    DSFENCE();  // prior iter's pa reads ordered before P overwrite
#pragma unroll
    for (int mi = 0; mi < 4; ++mi)
#pragma unroll
      for (int r = 0; r < 4; ++r) {
        const float p0 = EXP2(sacc[mi][0][r]);
        const float p1 = EXP2(sacc[mi][1][r]);
        lrun[mi][r] += p0 + p1;
        const ushort2 pp = pk_bf16(p0, p1);
        const int qrow = mi * 16 + quad * 4 + r;
        Psw[qrow * 40 + lan] = pp.x;
        Psw[qrow * 40 + 16 + lan] = pp.y;
      }
    DSFENCE();  // P visible/ordered before A-frag reads

    // O += P V : A-frag P[m=q][k=key(32)], B-frag V[n=dd][k=key]
    short8 pa[4];
#pragma unroll
    for (int mi = 0; mi < 4; ++mi)
      pa[mi] = *(const short8*)(Psw + (mi * 16 + lan) * 40 + quad * 8);
#pragma unroll
    for (int mi = 0; mi < 4; ++mi)
#pragma unroll
      for (int nd = 0; nd < 4; ++nd)
        oacc[mi][nd] = __builtin_amdgcn_mfma_f32_16x16x32_bf16(pa[mi], vb[nd], oacc[mi][nd], 0, 0, 0);
  }

  // ---- merge across waves (fixed-max => plain sums) ----
#pragma unroll
  for (int mi = 0; mi < 4; ++mi)
#pragma unroll
    for (int r = 0; r < 4; ++r) {
      float ls = lrun[mi][r];
#pragma unroll
      for (int d = 1; d < 16; d <<= 1) ls += __shfl_xor(ls, d);
      if (lan == 0) Lbuf[w * 64 + mi * 16 + quad * 4 + r] = ls;
    }
  __syncthreads();
  const int qm = tid >> 2, d0 = (tid & 3) * 4;
  const float linv =
      1.0f / (Lbuf[qm] + Lbuf[64 + qm] + Lbuf[128 + qm] + Lbuf[192 + qm]);
  float* Obuf = (float*)Pslds;  // reuse Ps region: per wave 1280 floats, rows of 17

#pragma unroll
  for (int nd = 0; nd < 4; ++nd) {
    __syncthreads();  // previous read phase done before overwrite
#pragma unroll
    for (int mi = 0; mi < 4; ++mi)
#pragma unroll
      for (int r = 0; r < 4; ++r)
        Obuf[w * 1280 + (mi * 16 + quad * 4 + r) * 17 + lan] = oacc[mi][nd][r];
    __syncthreads();
    ushort4 ov;
#pragma unroll
    for (int e = 0; e < 4; ++e) {
      const float s = Obuf[qm * 17 + d0 + e] + Obuf[1280 + qm * 17 + d0 + e] +
                      Obuf[2560 + qm * 17 + d0 + e] + Obuf[3840 + qm * 17 + d0 + e];
      ((u16*)&ov)[e] = f2bf(s * linv);
    }
    *(ushort4*)(O + (size_t)(b * 2048 + q0 + qm) * 1024 + h * 64 + nd * 16 + d0) = ov;
  }
}

extern "C" void kernel_launch(void* const* d_in, const int* in_sizes, int n_in,
                              void* d_out, int out_size, void* d_ws, size_t ws_size,
                              hipStream_t stream) {
  const float* query = (const float*)d_in[0];
  const float* key_ = (const float*)d_in[1];
  const float* value = (const float*)d_in[2];
  const float* Wq = (const float*)d_in[3];
  const float* bq = (const float*)d_in[4];
  const float* Wk = (const float*)d_in[5];
  const float* bk = (const float*)d_in[6];
  const float* Wv = (const float*)d_in[7];
  const float* bv = (const float*)d_in[8];
  const float* Wo = (const float*)d_in[9];
  const float* bo = (const float*)d_in[10];
  float* out = (float*)d_out;

  u16* ws = (u16*)d_ws;
  u16* Xq = ws;
  u16* Xk = ws + 4194304;
  u16* Xv = ws + 8388608;
  u16* cWq = ws + 12582912;
  u16* cWk = ws + 13631488;
  u16* cWv = ws + 14680064;
  u16* cWo = ws + 15728640;
  u16* cbq = ws + 16777216;
  u16* cbk = ws + 16779264;
  u16* cbv = ws + 16781312;
  u16* cbo = ws + 16783360;
  u16* Qw = ws + 17301504;
  u16* Kw = ws + 21495808;
  u16* Vtw = ws + 25690112;
  u16* Ow = ws + 29884416;

  cvt_kernel<<<16388, 256, 0, stream>>>(query, key_, value, Wq, Wk, Wv, Wo,
                                        bq, bk, bv, bo, ws);
  qkv_kernel<<<768, 256, 0, stream>>>(Xq, Xk, Xv, cWq, cWk, cWv, cbq, cbk, cbv,
                                      Qw, Kw, Vtw);
  attn_kernel<<<dim3(32, 32), 256, 0, stream>>>(Qw, Kw, Vtw, Ow);
  proj_kernel<<<256, 256, 0, stream>>>(Ow, cWo, cbo, out);
}

// Round 8
// 323.808 us; speedup vs baseline: 1.5373x; 1.5373x over previous
//
#include <hip/hip_runtime.h>
#include <hip/hip_bf16.h>

// MultiHeadAttention: B=2, S=2048, H=16, d=64, D=1024. I/O fp32; compute bf16 MFMA.
// [cvt] fp32->bf16 -> [qkv] X@W^T+b (Q pre-scaled by 0.125*log2e; K row-major;
// V as [B,H,64,2048]) -> [attn] flash attention: block-shared K LDS staging,
// V/Q fragments direct from global, fixed-max softmax, P via LDS (C->A transform)
// -> [proj] O@Wo^T+bo -> fp32 d_out.

typedef unsigned short u16;
typedef __attribute__((ext_vector_type(8))) short short8;   // 8 bf16 (MFMA A/B frag)
typedef __attribute__((ext_vector_type(4))) float floatx4;  // MFMA C/D frag

__device__ __forceinline__ float bf2f(u16 x) {
  return __uint_as_float(((unsigned)x) << 16);
}
__device__ __forceinline__ u16 f2bf(float f) {
  unsigned x = __float_as_uint(f);
  return (u16)((x + 0x7fffu + ((x >> 16) & 1u)) >> 16);  // RNE
}
__device__ __forceinline__ ushort2 pk_bf16(float a, float b) {
  __hip_bfloat162 h2 = __float22bfloat162_rn(make_float2(a, b));  // v_cvt_pk_bf16_f32
  ushort2 u;
  __builtin_memcpy(&u, &h2, 4);
  return u;
}
#if __has_builtin(__builtin_amdgcn_exp2f)
#define EXP2(x) __builtin_amdgcn_exp2f(x)
#else
#define EXP2(x) exp2f(x)
#endif
__device__ __forceinline__ void gll16(const u16* g, u16* lds) {
  __builtin_amdgcn_global_load_lds((const __attribute__((address_space(1))) void*)g,
                                   (__attribute__((address_space(3))) void*)lds,
                                   16, 0, 0);
}
// Compiler reorder barrier + DS drain (doesn't touch vmcnt: global loads in flight)
#define DSFENCE() __asm__ volatile("s_waitcnt lgkmcnt(0)" ::: "memory")

// ---------------------------------------------------------------------------
// fp32 -> bf16 of all 11 inputs. 16388 blocks x 256 thr x 4 elem, exact cover.
// ---------------------------------------------------------------------------
__global__ __launch_bounds__(256) void cvt_kernel(
    const float* __restrict__ q, const float* __restrict__ k, const float* __restrict__ v,
    const float* __restrict__ wq, const float* __restrict__ wk,
    const float* __restrict__ wv, const float* __restrict__ wo,
    const float* __restrict__ bq, const float* __restrict__ bk,
    const float* __restrict__ bv, const float* __restrict__ bo,
    u16* __restrict__ ws) {
  const int i4 = (blockIdx.x * 256 + threadIdx.x) * 4;
  const float* src;
  u16* dst;
  int local;
  if (i4 < 4194304)        { src = q;  dst = ws;            local = i4; }
  else if (i4 < 8388608)   { src = k;  dst = ws + 4194304;  local = i4 - 4194304; }
  else if (i4 < 12582912)  { src = v;  dst = ws + 8388608;  local = i4 - 8388608; }
  else if (i4 < 13631488)  { src = wq; dst = ws + 12582912; local = i4 - 12582912; }
  else if (i4 < 14680064)  { src = wk; dst = ws + 13631488; local = i4 - 13631488; }
  else if (i4 < 15728640)  { src = wv; dst = ws + 14680064; local = i4 - 14680064; }
  else if (i4 < 16777216)  { src = wo; dst = ws + 15728640; local = i4 - 15728640; }
  else if (i4 < 16778240)  { src = bq; dst = ws + 16777216; local = i4 - 16777216; }
  else if (i4 < 16779264)  { src = bk; dst = ws + 16779264; local = i4 - 16778240; }
  else if (i4 < 16780288)  { src = bv; dst = ws + 16781312; local = i4 - 16779264; }
  else                     { src = bo; dst = ws + 16783360; local = i4 - 16780288; }
  const float4 f = *(const float4*)(src + local);
  ushort4 o;
  o.x = f2bf(f.x); o.y = f2bf(f.y); o.z = f2bf(f.z); o.w = f2bf(f.w);
  *(ushort4*)(dst + local) = o;
}

// ---------------------------------------------------------------------------
// GEMM tile (m97 structure): out[m][n] = (X[m][:].W[n][:] + bias[n]) * oscale
// 256 thr (2x2 waves of 64x64), tile 128x128, BK=32, gll16 width-16 staging.
// mode 0: bf16 row-major. mode 1: bf16 [b][h][dd][s]. mode 2: fp32 row-major.
// ---------------------------------------------------------------------------
__device__ __forceinline__ void gemm_tile(
    const u16* __restrict__ X, const u16* __restrict__ W,
    const u16* __restrict__ bias, u16* __restrict__ out16, float* __restrict__ out32,
    int row0, int col0, int mode, float oscale, u16* As, u16* Bs) {
  const int tid = threadIdx.x;
  const int w = tid >> 6, l = tid & 63;
  const int lan = l & 15, quad = l >> 4;
  const int wm = w & 1, wn = w >> 1;

  floatx4 acc[4][4];
#pragma unroll
  for (int i = 0; i < 4; ++i)
#pragma unroll
    for (int j = 0; j < 4; ++j) acc[i][j] = (floatx4)0.0f;

  const int r0 = tid >> 2, kq0 = tid & 3;
  const int r1 = (tid + 256) >> 2;
  u16* aB0 = As + w * 512;
  u16* aB1 = As + 2048 + w * 512;
  u16* bB0 = Bs + w * 512;
  u16* bB1 = Bs + 2048 + w * 512;
  const u16* Xa0 = X + (size_t)(row0 + r0) * 1024 + kq0 * 8;
  const u16* Xa1 = X + (size_t)(row0 + r1) * 1024 + kq0 * 8;
  const u16* Wb0 = W + (size_t)(col0 + r0) * 1024 + kq0 * 8;
  const u16* Wb1 = W + (size_t)(col0 + r1) * 1024 + kq0 * 8;

  for (int kt = 0; kt < 32; ++kt) {
    gll16(Xa0 + kt * 32, aB0);
    gll16(Xa1 + kt * 32, aB1);
    gll16(Wb0 + kt * 32, bB0);
    gll16(Wb1 + kt * 32, bB1);
    __syncthreads();

    short8 af[4], bfr[4];
#pragma unroll
    for (int i = 0; i < 4; ++i)
      af[i] = *(const short8*)(As + (wm * 64 + i * 16 + lan) * 32 + quad * 8);
#pragma unroll
    for (int j = 0; j < 4; ++j)
      bfr[j] = *(const short8*)(Bs + (wn * 64 + j * 16 + lan) * 32 + quad * 8);
#pragma unroll
    for (int i = 0; i < 4; ++i)
#pragma unroll
      for (int j = 0; j < 4; ++j)
        acc[i][j] = __builtin_amdgcn_mfma_f32_16x16x32_bf16(af[i], bfr[j], acc[i][j], 0, 0, 0);
    __syncthreads();
  }

#pragma unroll
  for (int i = 0; i < 4; ++i) {
    const int mb = row0 + wm * 64 + i * 16 + quad * 4;
#pragma unroll
    for (int j = 0; j < 4; ++j) {
      const int n = col0 + wn * 64 + j * 16 + lan;
      const float bv = bf2f(bias[n]);
      if (mode == 0) {
#pragma unroll
        for (int r = 0; r < 4; ++r)
          out16[(size_t)(mb + r) * 1024 + n] = f2bf((acc[i][j][r] + bv) * oscale);
      } else if (mode == 1) {
        const int b = mb >> 11, s = mb & 2047;
        const int h = n >> 6, dd = n & 63;
        ushort4 v;
        v.x = f2bf(acc[i][j][0] + bv);
        v.y = f2bf(acc[i][j][1] + bv);
        v.z = f2bf(acc[i][j][2] + bv);
        v.w = f2bf(acc[i][j][3] + bv);
        *(ushort4*)(out16 + (size_t)((b * 16 + h) * 64 + dd) * 2048 + s) = v;
      } else {
#pragma unroll
        for (int r = 0; r < 4; ++r)
          out32[(size_t)(mb + r) * 1024 + n] = acc[i][j][r] + bv;
      }
    }
  }
}

__global__ __launch_bounds__(256) void qkv_kernel(
    const u16* __restrict__ xq, const u16* __restrict__ xk, const u16* __restrict__ xv,
    const u16* __restrict__ Wq, const u16* __restrict__ Wk, const u16* __restrict__ Wv,
    const u16* __restrict__ bq, const u16* __restrict__ bk, const u16* __restrict__ bv,
    u16* __restrict__ Qo, u16* __restrict__ Ko, u16* __restrict__ Vto) {
  __shared__ __align__(16) u16 As[128 * 32];
  __shared__ __align__(16) u16 Bs[128 * 32];
  const int bx = blockIdx.x;           // 0..767
  const int tile_m = bx / 24;
  const int rem = bx - tile_m * 24;
  const int which = rem >> 3;          // 0=Q 1=K 2=V
  const int col0 = (rem & 7) * 128;
  const u16* X = which == 0 ? xq : (which == 1 ? xk : xv);
  const u16* W = which == 0 ? Wq : (which == 1 ? Wk : Wv);
  const u16* bias = which == 0 ? bq : (which == 1 ? bk : bv);
  u16* out = which == 0 ? Qo : (which == 1 ? Ko : Vto);
  const float C = 0.125f * 1.4426950408889634f;  // fold scale*log2e into Q
  gemm_tile(X, W, bias, out, nullptr, tile_m * 128, col0, which == 2 ? 1 : 0,
            which == 0 ? C : 1.0f, As, Bs);
}

__global__ __launch_bounds__(256) void proj_kernel(
    const u16* __restrict__ X, const u16* __restrict__ W,
    const u16* __restrict__ bias, float* __restrict__ out) {
  __shared__ __align__(16) u16 As[128 * 32];
  __shared__ __align__(16) u16 Bs[128 * 32];
  const int bx = blockIdx.x;  // 0..255
  gemm_tile(X, W, bias, nullptr, out, (bx >> 3) * 128, (bx & 7) * 128, 2, 1.0f, As, Bs);
}

// ---------------------------------------------------------------------------
// Flash attention v6 (r5 skeleton + surgical cuts). grid (32 qtiles of 64, 32 bh),
// 256 thr; wave owns 16 q rows, all 64 keys of each K-tile. Fixed-max softmax
// (p=exp2(C*qk-16); C folded into Q, -16 in sacc init).
//  - K: block-shared LDS staging (stride 72), register-prefetched one tile ahead.
//  - Q: A-frags direct from global, once.
//  - V: B-frags direct from global each kt (Vt layout IS B-frag layout); loaded at
//    iteration top, consumed after softmax -> in-iteration latency hiding.
//  - P: LDS round-trip (C->A transform), stride 72, wave-private rows.
// LDS ~19.5 KB; softmax uses raw v_exp_f32 + packed bf16 converts.
// ---------------------------------------------------------------------------
#define FIXMAX 16.0f
#define KPAD 72
__global__ __launch_bounds__(256, 3) void attn_kernel(
    const u16* __restrict__ Q, const u16* __restrict__ K,
    const u16* __restrict__ Vt, u16* __restrict__ O) {
  __shared__ __align__(16) u16 Ks[64 * KPAD];  // [key][dd]
  __shared__ __align__(16) u16 Ps[64 * KPAD];  // [q][key]
  __shared__ float Lbuf[64];                   // unused pad (kept for alignment)
  const int tid = threadIdx.x;
  const int w = tid >> 6, l = tid & 63;
  const int lan = l & 15, quad = l >> 4;
  const int q0 = blockIdx.x * 64;
  const int bh = blockIdx.y;
  const int b = bh >> 4, h = bh & 15;
  const u16* Qg = Q + (size_t)(b * 2048 + q0) * 1024 + h * 64;
  const u16* Kg = K + (size_t)(b * 2048) * 1024 + h * 64;
  const u16* Vg = Vt + (size_t)((b * 16 + h) * 64) * 2048;
  (void)Lbuf;

  // Q A-frags direct from global: rows w*16+lan, k = kk*32+quad*8+j  (16 rows x 64B)
  short8 aq[2];
#pragma unroll
  for (int kk = 0; kk < 2; ++kk)
    aq[kk] = *(const short8*)(Qg + (size_t)(w * 16 + lan) * 1024 + kk * 32 + quad * 8);

  float lrun[4];
  floatx4 oacc[4];
#pragma unroll
  for (int r = 0; r < 4; ++r) lrun[r] = 0.f;
#pragma unroll
  for (int nd = 0; nd < 4; ++nd) oacc[nd] = (floatx4)0.0f;

  // K staging map: 64 rows x 8 chunks of 16B = 512 chunks, 2/thread
  const int rowA = tid >> 3, colq = (tid & 7) * 8;  // rows 0..31
  const int rowB = rowA + 32;                       // rows 32..63

  // prefetch K tile 0
  short8 k0 = *(const short8*)(Kg + (size_t)rowA * 1024 + colq);
  short8 k1 = *(const short8*)(Kg + (size_t)rowB * 1024 + colq);

  for (int kt = 0; kt < 32; ++kt) {
    __syncthreads();  // prior iteration's Ks reads complete
    *(short8*)(Ks + rowA * KPAD + colq) = k0;
    *(short8*)(Ks + rowB * KPAD + colq) = k1;
    __syncthreads();  // staging visible

    // prefetch next K tile (overlaps this iteration's compute)
    const int kn = kt < 31 ? kt + 1 : 31;
    k0 = *(const short8*)(Kg + (size_t)(kn * 64 + rowA) * 1024 + colq);
    k1 = *(const short8*)(Kg + (size_t)(kn * 64 + rowB) * 1024 + colq);

    // V B-frags direct from global (consumed after softmax -> latency hidden)
    short8 vb[4][2];
#pragma unroll
    for (int nd = 0; nd < 4; ++nd)
#pragma unroll
      for (int kk = 0; kk < 2; ++kk)
        vb[nd][kk] = *(const short8*)(Vg + (size_t)(nd * 16 + lan) * 2048 + kt * 64 +
                                      kk * 32 + quad * 8);

    // S = Q K^T : 16q x 64keys per wave. B-frag: K[n=key][k=dd]
    short8 bkf[4][2];
#pragma unroll
    for (int nj = 0; nj < 4; ++nj)
#pragma unroll
      for (int kk = 0; kk < 2; ++kk)
        bkf[nj][kk] = *(const short8*)(Ks + (nj * 16 + lan) * KPAD + kk * 32 + quad * 8);

    floatx4 sacc[4];
#pragma unroll
    for (int nj = 0; nj < 4; ++nj) sacc[nj] = (floatx4)(-FIXMAX);
#pragma unroll
    for (int kk = 0; kk < 2; ++kk)
#pragma unroll
      for (int nj = 0; nj < 4; ++nj)
        sacc[nj] = __builtin_amdgcn_mfma_f32_16x16x32_bf16(aq[kk], bkf[nj][kk], sacc[nj], 0, 0, 0);

    // fixed-max softmax; C/D: row=quad*4+r, col=lan per nj tile
#pragma unroll
    for (int r = 0; r < 4; ++r) {
      const float p0 = EXP2(sacc[0][r]), p1 = EXP2(sacc[1][r]);
      const float p2 = EXP2(sacc[2][r]), p3 = EXP2(sacc[3][r]);
      lrun[r] += (p0 + p1) + (p2 + p3);
      const ushort2 pa01 = pk_bf16(p0, p1);
      const ushort2 pa23 = pk_bf16(p2, p3);
      const int qrow = w * 16 + quad * 4 + r;
      Ps[qrow * KPAD + lan] = pa01.x;
      Ps[qrow * KPAD + 16 + lan] = pa01.y;
      Ps[qrow * KPAD + 32 + lan] = pa23.x;
      Ps[qrow * KPAD + 48 + lan] = pa23.y;
    }
    DSFENCE();  // P writes ordered/visible before same-wave A-frag reads

    // O += P V : A-frag P[m=q][k=key], B-frag V[n=dd][k=key]
    short8 pa[2];
#pragma unroll
    for (int kk = 0; kk < 2; ++kk)
      pa[kk] = *(const short8*)(Ps + (w * 16 + lan) * KPAD + kk * 32 + quad * 8);
#pragma unroll
    for (int kk = 0; kk < 2; ++kk)
#pragma unroll
      for (int nd = 0; nd < 4; ++nd)
        oacc[nd] = __builtin_amdgcn_mfma_f32_16x16x32_bf16(pa[kk], vb[nd][kk], oacc[nd], 0, 0, 0);
    // loop-top barrier protects Ks before next overwrite; Ps rows are wave-private
  }

  // reduce lane-distributed lrun across the 16-lane group, store O
#pragma unroll
  for (int r = 0; r < 4; ++r) {
    float ls = lrun[r];
#pragma unroll
    for (int d = 1; d < 16; d <<= 1) ls += __shfl_xor(ls, d);
    const float inv = 1.0f / ls;
    const int mg = b * 2048 + q0 + w * 16 + quad * 4 + r;
#pragma unroll
    for (int nd = 0; nd < 4; ++nd) {
      const int col = h * 64 + nd * 16 + lan;
      O[(size_t)mg * 1024 + col] = f2bf(oacc[nd][r] * inv);
    }
  }
}

extern "C" void kernel_launch(void* const* d_in, const int* in_sizes, int n_in,
                              void* d_out, int out_size, void* d_ws, size_t ws_size,
                              hipStream_t stream) {
  const float* query = (const float*)d_in[0];
  const float* key_ = (const float*)d_in[1];
  const float* value = (const float*)d_in[2];
  const float* Wq = (const float*)d_in[3];
  const float* bq = (const float*)d_in[4];
  const float* Wk = (const float*)d_in[5];
  const float* bk = (const float*)d_in[6];
  const float* Wv = (const float*)d_in[7];
  const float* bv = (const float*)d_in[8];
  const float* Wo = (const float*)d_in[9];
  const float* bo = (const float*)d_in[10];
  float* out = (float*)d_out;

  u16* ws = (u16*)d_ws;
  u16* Xq = ws;
  u16* Xk = ws + 4194304;
  u16* Xv = ws + 8388608;
  u16* cWq = ws + 12582912;
  u16* cWk = ws + 13631488;
  u16* cWv = ws + 14680064;
  u16* cWo = ws + 15728640;
  u16* cbq = ws + 16777216;
  u16* cbk = ws + 16779264;
  u16* cbv = ws + 16781312;
  u16* cbo = ws + 16783360;
  u16* Qw = ws + 17301504;
  u16* Kw = ws + 21495808;
  u16* Vtw = ws + 25690112;
  u16* Ow = ws + 29884416;

  cvt_kernel<<<16388, 256, 0, stream>>>(query, key_, value, Wq, Wk, Wv, Wo,
                                        bq, bk, bv, bo, ws);
  qkv_kernel<<<768, 256, 0, stream>>>(Xq, Xk, Xv, cWq, cWk, cWv, cbq, cbk, cbv,
                                      Qw, Kw, Vtw);
  attn_kernel<<<dim3(32, 32), 256, 0, stream>>>(Qw, Kw, Vtw, Ow);
  proj_kernel<<<256, 256, 0, stream>>>(Ow, cWo, cbo, out);
}

// Round 9
// 249.330 us; speedup vs baseline: 1.9965x; 1.2987x over previous
//
#include <hip/hip_runtime.h>
#include <hip/hip_bf16.h>

// MultiHeadAttention: B=2, S=2048, H=16, d=64, D=1024. I/O fp32; compute bf16 MFMA.
// [cvt] fp32->bf16 -> [qkv] X@W^T+b (Q pre-scaled by 0.125*log2e; K row-major;
// V as [B,H,64,2048] with keys PERMUTED within each 64-block: k'=(k&15)*4+(k>>4))
// -> [attn] flash attention (K/V LDS-staged coalesced, fixed-max softmax, packed
// b64 P writes matching the V permutation) -> [proj] O@Wo^T+bo -> fp32 d_out.
// LAW (r7/r8): MFMA fragments are lane-granular gathers -> always read them from
// LDS; keep all global accesses contiguous (staging loads / scatter stores only).

typedef unsigned short u16;
typedef __attribute__((ext_vector_type(8))) short short8;   // 8 bf16 (MFMA A/B frag)
typedef __attribute__((ext_vector_type(4))) float floatx4;  // MFMA C/D frag

__device__ __forceinline__ float bf2f(u16 x) {
  return __uint_as_float(((unsigned)x) << 16);
}
__device__ __forceinline__ u16 f2bf(float f) {
  unsigned x = __float_as_uint(f);
  return (u16)((x + 0x7fffu + ((x >> 16) & 1u)) >> 16);  // RNE
}
__device__ __forceinline__ ushort2 pk_bf16(float a, float b) {
  __hip_bfloat162 h2 = __float22bfloat162_rn(make_float2(a, b));  // v_cvt_pk_bf16_f32
  ushort2 u;
  __builtin_memcpy(&u, &h2, 4);
  return u;
}
#if __has_builtin(__builtin_amdgcn_exp2f)
#define EXP2(x) __builtin_amdgcn_exp2f(x)
#else
#define EXP2(x) exp2f(x)
#endif
__device__ __forceinline__ void gll16(const u16* g, u16* lds) {
  __builtin_amdgcn_global_load_lds((const __attribute__((address_space(1))) void*)g,
                                   (__attribute__((address_space(3))) void*)lds,
                                   16, 0, 0);
}
// Compiler reorder barrier + DS drain (doesn't touch vmcnt: global loads in flight)
#define DSFENCE() __asm__ volatile("s_waitcnt lgkmcnt(0)" ::: "memory")

// ---------------------------------------------------------------------------
// fp32 -> bf16 of all 11 inputs. 16388 blocks x 256 thr x 4 elem, exact cover.
// ---------------------------------------------------------------------------
__global__ __launch_bounds__(256) void cvt_kernel(
    const float* __restrict__ q, const float* __restrict__ k, const float* __restrict__ v,
    const float* __restrict__ wq, const float* __restrict__ wk,
    const float* __restrict__ wv, const float* __restrict__ wo,
    const float* __restrict__ bq, const float* __restrict__ bk,
    const float* __restrict__ bv, const float* __restrict__ bo,
    u16* __restrict__ ws) {
  const int i4 = (blockIdx.x * 256 + threadIdx.x) * 4;
  const float* src;
  u16* dst;
  int local;
  if (i4 < 4194304)        { src = q;  dst = ws;            local = i4; }
  else if (i4 < 8388608)   { src = k;  dst = ws + 4194304;  local = i4 - 4194304; }
  else if (i4 < 12582912)  { src = v;  dst = ws + 8388608;  local = i4 - 8388608; }
  else if (i4 < 13631488)  { src = wq; dst = ws + 12582912; local = i4 - 12582912; }
  else if (i4 < 14680064)  { src = wk; dst = ws + 13631488; local = i4 - 13631488; }
  else if (i4 < 15728640)  { src = wv; dst = ws + 14680064; local = i4 - 14680064; }
  else if (i4 < 16777216)  { src = wo; dst = ws + 15728640; local = i4 - 15728640; }
  else if (i4 < 16778240)  { src = bq; dst = ws + 16777216; local = i4 - 16777216; }
  else if (i4 < 16779264)  { src = bk; dst = ws + 16779264; local = i4 - 16778240; }
  else if (i4 < 16780288)  { src = bv; dst = ws + 16781312; local = i4 - 16779264; }
  else                     { src = bo; dst = ws + 16783360; local = i4 - 16780288; }
  const float4 f = *(const float4*)(src + local);
  ushort4 o;
  o.x = f2bf(f.x); o.y = f2bf(f.y); o.z = f2bf(f.z); o.w = f2bf(f.w);
  *(ushort4*)(dst + local) = o;
}

// ---------------------------------------------------------------------------
// GEMM tile (m97 structure): out[m][n] = (X[m][:].W[n][:] + bias[n]) * oscale
// 256 thr (2x2 waves of 64x64), tile 128x128, BK=32, gll16 width-16 staging.
// mode 0: bf16 row-major. mode 1: bf16 [b][h][dd][s'] (s' = key-permuted within
// 64-blocks: k'=(k&15)*4+(k>>4)). mode 2: fp32 row-major.
// ---------------------------------------------------------------------------
__device__ __forceinline__ void gemm_tile(
    const u16* __restrict__ X, const u16* __restrict__ W,
    const u16* __restrict__ bias, u16* __restrict__ out16, float* __restrict__ out32,
    int row0, int col0, int mode, float oscale, u16* As, u16* Bs) {
  const int tid = threadIdx.x;
  const int w = tid >> 6, l = tid & 63;
  const int lan = l & 15, quad = l >> 4;
  const int wm = w & 1, wn = w >> 1;

  floatx4 acc[4][4];
#pragma unroll
  for (int i = 0; i < 4; ++i)
#pragma unroll
    for (int j = 0; j < 4; ++j) acc[i][j] = (floatx4)0.0f;

  const int r0 = tid >> 2, kq0 = tid & 3;
  const int r1 = (tid + 256) >> 2;
  u16* aB0 = As + w * 512;
  u16* aB1 = As + 2048 + w * 512;
  u16* bB0 = Bs + w * 512;
  u16* bB1 = Bs + 2048 + w * 512;
  const u16* Xa0 = X + (size_t)(row0 + r0) * 1024 + kq0 * 8;
  const u16* Xa1 = X + (size_t)(row0 + r1) * 1024 + kq0 * 8;
  const u16* Wb0 = W + (size_t)(col0 + r0) * 1024 + kq0 * 8;
  const u16* Wb1 = W + (size_t)(col0 + r1) * 1024 + kq0 * 8;

  for (int kt = 0; kt < 32; ++kt) {
    gll16(Xa0 + kt * 32, aB0);
    gll16(Xa1 + kt * 32, aB1);
    gll16(Wb0 + kt * 32, bB0);
    gll16(Wb1 + kt * 32, bB1);
    __syncthreads();

    short8 af[4], bfr[4];
#pragma unroll
    for (int i = 0; i < 4; ++i)
      af[i] = *(const short8*)(As + (wm * 64 + i * 16 + lan) * 32 + quad * 8);
#pragma unroll
    for (int j = 0; j < 4; ++j)
      bfr[j] = *(const short8*)(Bs + (wn * 64 + j * 16 + lan) * 32 + quad * 8);
#pragma unroll
    for (int i = 0; i < 4; ++i)
#pragma unroll
      for (int j = 0; j < 4; ++j)
        acc[i][j] = __builtin_amdgcn_mfma_f32_16x16x32_bf16(af[i], bfr[j], acc[i][j], 0, 0, 0);
    __syncthreads();
  }

#pragma unroll
  for (int i = 0; i < 4; ++i) {
    const int mb = row0 + wm * 64 + i * 16 + quad * 4;
#pragma unroll
    for (int j = 0; j < 4; ++j) {
      const int n = col0 + wn * 64 + j * 16 + lan;
      const float bv = bf2f(bias[n]);
      if (mode == 0) {
#pragma unroll
        for (int r = 0; r < 4; ++r)
          out16[(size_t)(mb + r) * 1024 + n] = f2bf((acc[i][j][r] + bv) * oscale);
      } else if (mode == 1) {
        // V head-transposed + key-permuted: token s -> slot (s&~63)|((s&15)*4+((s>>4)&3))
        const int b = mb >> 11;
        const int h = n >> 6, dd = n & 63;
        u16* base = out16 + (size_t)((b * 16 + h) * 64 + dd) * 2048;
#pragma unroll
        for (int r = 0; r < 4; ++r) {
          const int s = (mb + r) & 2047;
          const int sp = (s & ~63) | ((s & 15) * 4 + ((s >> 4) & 3));
          base[sp] = f2bf(acc[i][j][r] + bv);
        }
      } else {
#pragma unroll
        for (int r = 0; r < 4; ++r)
          out32[(size_t)(mb + r) * 1024 + n] = acc[i][j][r] + bv;
      }
    }
  }
}

__global__ __launch_bounds__(256) void qkv_kernel(
    const u16* __restrict__ xq, const u16* __restrict__ xk, const u16* __restrict__ xv,
    const u16* __restrict__ Wq, const u16* __restrict__ Wk, const u16* __restrict__ Wv,
    const u16* __restrict__ bq, const u16* __restrict__ bk, const u16* __restrict__ bv,
    u16* __restrict__ Qo, u16* __restrict__ Ko, u16* __restrict__ Vto) {
  __shared__ __align__(16) u16 As[128 * 32];
  __shared__ __align__(16) u16 Bs[128 * 32];
  const int bx = blockIdx.x;           // 0..767
  const int tile_m = bx / 24;
  const int rem = bx - tile_m * 24;
  const int which = rem >> 3;          // 0=Q 1=K 2=V
  const int col0 = (rem & 7) * 128;
  const u16* X = which == 0 ? xq : (which == 1 ? xk : xv);
  const u16* W = which == 0 ? Wq : (which == 1 ? Wk : Wv);
  const u16* bias = which == 0 ? bq : (which == 1 ? bk : bv);
  u16* out = which == 0 ? Qo : (which == 1 ? Ko : Vto);
  const float C = 0.125f * 1.4426950408889634f;  // fold scale*log2e into Q
  gemm_tile(X, W, bias, out, nullptr, tile_m * 128, col0, which == 2 ? 1 : 0,
            which == 0 ? C : 1.0f, As, Bs);
}

__global__ __launch_bounds__(256) void proj_kernel(
    const u16* __restrict__ X, const u16* __restrict__ W,
    const u16* __restrict__ bias, float* __restrict__ out) {
  __shared__ __align__(16) u16 As[128 * 32];
  __shared__ __align__(16) u16 Bs[128 * 32];
  const int bx = blockIdx.x;  // 0..255
  gemm_tile(X, W, bias, nullptr, out, (bx >> 3) * 128, (bx & 7) * 128, 2, 1.0f, As, Bs);
}

// ---------------------------------------------------------------------------
// Flash attention v7 (r5 skeleton + VALU cut + packed P). grid (32 qtiles, 32 bh),
// 256 thr, 4 waves each owning 16 q rows x all 64 keys of the tile.
//  - K/V: coalesced LDS staging (stride 72), register-prefetched one tile ahead.
//  - Q: A-frags direct from global once (16 rows x 64B contiguous -> coalesced).
//  - softmax: fixed-max (p=exp2(C*qk-16)), raw v_exp_f32 + packed bf16 cvt.
//  - P: ONE ushort4 (b64) LDS write per row (key-permuted layout k'=lan*4+nj,
//    matching V's global permutation from the qkv epilogue).
// LDS 3x9216B = 27.6 KB -> 4 blocks/CU at VGPR<=128 (launch_bounds(256,4)).
// ---------------------------------------------------------------------------
#define FIXMAX 16.0f
#define KPAD 72
__global__ __launch_bounds__(256, 4) void attn_kernel(
    const u16* __restrict__ Q, const u16* __restrict__ K,
    const u16* __restrict__ Vt, u16* __restrict__ O) {
  __shared__ __align__(16) u16 Ks[64 * KPAD];  // [key][dd]
  __shared__ __align__(16) u16 Vs[64 * KPAD];  // [dd][key']
  __shared__ __align__(16) u16 Ps[64 * KPAD];  // [q][key']
  const int tid = threadIdx.x;
  const int w = tid >> 6, l = tid & 63;
  const int lan = l & 15, quad = l >> 4;
  const int q0 = blockIdx.x * 64;
  const int bh = blockIdx.y;
  const int b = bh >> 4, h = bh & 15;
  const u16* Qg = Q + (size_t)(b * 2048 + q0) * 1024 + h * 64;
  const u16* Kg = K + (size_t)(b * 2048) * 1024 + h * 64;
  const u16* Vg = Vt + (size_t)((b * 16 + h) * 64) * 2048;

  // Q A-frags direct from global: rows w*16+lan (16 x 64B contiguous), once.
  short8 aq[2];
#pragma unroll
  for (int kk = 0; kk < 2; ++kk)
    aq[kk] = *(const short8*)(Qg + (size_t)(w * 16 + lan) * 1024 + kk * 32 + quad * 8);

  float lrun[4];
  floatx4 oacc[4];
#pragma unroll
  for (int r = 0; r < 4; ++r) lrun[r] = 0.f;
#pragma unroll
  for (int nd = 0; nd < 4; ++nd) oacc[nd] = (floatx4)0.0f;

  // staging maps: 64 rows x 8 chunks of 16B = 512 chunks, 2/thread (coalesced)
  const int rowA = tid >> 3, colq = (tid & 7) * 8;  // rows 0..31
  const int rowB = rowA + 32;                       // rows 32..63

  // prefetch tile 0 (K rows = keys; V rows = dd, cols already key-permuted)
  short8 k0 = *(const short8*)(Kg + (size_t)rowA * 1024 + colq);
  short8 k1 = *(const short8*)(Kg + (size_t)rowB * 1024 + colq);
  short8 v0 = *(const short8*)(Vg + (size_t)rowA * 2048 + colq);
  short8 v1 = *(const short8*)(Vg + (size_t)rowB * 2048 + colq);

  for (int kt = 0; kt < 32; ++kt) {
    __syncthreads();  // prior iteration's Ks/Vs reads complete
    *(short8*)(Ks + rowA * KPAD + colq) = k0;
    *(short8*)(Ks + rowB * KPAD + colq) = k1;
    *(short8*)(Vs + rowA * KPAD + colq) = v0;
    *(short8*)(Vs + rowB * KPAD + colq) = v1;
    __syncthreads();  // staging visible

    // prefetch next tile (in flight across this iteration's compute)
    const int kn = kt < 31 ? kt + 1 : 31;
    k0 = *(const short8*)(Kg + (size_t)(kn * 64 + rowA) * 1024 + colq);
    k1 = *(const short8*)(Kg + (size_t)(kn * 64 + rowB) * 1024 + colq);
    v0 = *(const short8*)(Vg + (size_t)rowA * 2048 + kn * 64 + colq);
    v1 = *(const short8*)(Vg + (size_t)rowB * 2048 + kn * 64 + colq);

    // S = Q K^T : 16q x 64keys per wave. B-frag: K[n=key][k=dd]
    short8 bkf[4][2];
#pragma unroll
    for (int nj = 0; nj < 4; ++nj)
#pragma unroll
      for (int kk = 0; kk < 2; ++kk)
        bkf[nj][kk] = *(const short8*)(Ks + (nj * 16 + lan) * KPAD + kk * 32 + quad * 8);

    floatx4 sacc[4];
#pragma unroll
    for (int nj = 0; nj < 4; ++nj) sacc[nj] = (floatx4)(-FIXMAX);
#pragma unroll
    for (int kk = 0; kk < 2; ++kk)
#pragma unroll
      for (int nj = 0; nj < 4; ++nj)
        sacc[nj] = __builtin_amdgcn_mfma_f32_16x16x32_bf16(aq[kk], bkf[nj][kk], sacc[nj], 0, 0, 0);

    // fixed-max softmax; lane holds cols lan+{0,16,32,48} -> packed slot lan*4+nj
#pragma unroll
    for (int r = 0; r < 4; ++r) {
      const float p0 = EXP2(sacc[0][r]), p1 = EXP2(sacc[1][r]);
      const float p2 = EXP2(sacc[2][r]), p3 = EXP2(sacc[3][r]);
      lrun[r] += (p0 + p1) + (p2 + p3);
      const ushort2 a01 = pk_bf16(p0, p1);
      const ushort2 a23 = pk_bf16(p2, p3);
      ushort4 pp;
      pp.x = a01.x; pp.y = a01.y; pp.z = a23.x; pp.w = a23.y;
      const int qrow = w * 16 + quad * 4 + r;
      *(ushort4*)(Ps + qrow * KPAD + lan * 4) = pp;  // ONE b64 write
    }
    DSFENCE();  // P writes ordered/visible before same-wave A-frag reads

    // O += P V : A-frag P[m=q][k'], B-frag V[n=dd][k'] (same permutation)
    short8 pa[2];
#pragma unroll
    for (int kk = 0; kk < 2; ++kk)
      pa[kk] = *(const short8*)(Ps + (w * 16 + lan) * KPAD + kk * 32 + quad * 8);
    short8 vb[4][2];
#pragma unroll
    for (int nd = 0; nd < 4; ++nd)
#pragma unroll
      for (int kk = 0; kk < 2; ++kk)
        vb[nd][kk] = *(const short8*)(Vs + (nd * 16 + lan) * KPAD + kk * 32 + quad * 8);
#pragma unroll
    for (int kk = 0; kk < 2; ++kk)
#pragma unroll
      for (int nd = 0; nd < 4; ++nd)
        oacc[nd] = __builtin_amdgcn_mfma_f32_16x16x32_bf16(pa[kk], vb[nd][kk], oacc[nd], 0, 0, 0);
  }

  // reduce lane-distributed lrun across the 16-lane group, store O
#pragma unroll
  for (int r = 0; r < 4; ++r) {
    float ls = lrun[r];
#pragma unroll
    for (int d = 1; d < 16; d <<= 1) ls += __shfl_xor(ls, d);
    const float inv = 1.0f / ls;
    const int mg = b * 2048 + q0 + w * 16 + quad * 4 + r;
#pragma unroll
    for (int nd = 0; nd < 4; ++nd) {
      const int col = h * 64 + nd * 16 + lan;
      O[(size_t)mg * 1024 + col] = f2bf(oacc[nd][r] * inv);
    }
  }
}

extern "C" void kernel_launch(void* const* d_in, const int* in_sizes, int n_in,
                              void* d_out, int out_size, void* d_ws, size_t ws_size,
                              hipStream_t stream) {
  const float* query = (const float*)d_in[0];
  const float* key_ = (const float*)d_in[1];
  const float* value = (const float*)d_in[2];
  const float* Wq = (const float*)d_in[3];
  const float* bq = (const float*)d_in[4];
  const float* Wk = (const float*)d_in[5];
  const float* bk = (const float*)d_in[6];
  const float* Wv = (const float*)d_in[7];
  const float* bv = (const float*)d_in[8];
  const float* Wo = (const float*)d_in[9];
  const float* bo = (const float*)d_in[10];
  float* out = (float*)d_out;

  u16* ws = (u16*)d_ws;
  u16* Xq = ws;
  u16* Xk = ws + 4194304;
  u16* Xv = ws + 8388608;
  u16* cWq = ws + 12582912;
  u16* cWk = ws + 13631488;
  u16* cWv = ws + 14680064;
  u16* cWo = ws + 15728640;
  u16* cbq = ws + 16777216;
  u16* cbk = ws + 16779264;
  u16* cbv = ws + 16781312;
  u16* cbo = ws + 16783360;
  u16* Qw = ws + 17301504;
  u16* Kw = ws + 21495808;
  u16* Vtw = ws + 25690112;
  u16* Ow = ws + 29884416;

  cvt_kernel<<<16388, 256, 0, stream>>>(query, key_, value, Wq, Wk, Wv, Wo,
                                        bq, bk, bv, bo, ws);
  qkv_kernel<<<768, 256, 0, stream>>>(Xq, Xk, Xv, cWq, cWk, cWv, cbq, cbk, cbv,
                                      Qw, Kw, Vtw);
  attn_kernel<<<dim3(32, 32), 256, 0, stream>>>(Qw, Kw, Vtw, Ow);
  proj_kernel<<<256, 256, 0, stream>>>(Ow, cWo, cbo, out);
}

// Round 10
// 238.012 us; speedup vs baseline: 2.0914x; 1.0476x over previous
//
#include <hip/hip_runtime.h>
#include <hip/hip_bf16.h>

// MultiHeadAttention: B=2, S=2048, H=16, d=64, D=1024. I/O fp32; compute bf16 MFMA.
// [cvt] fp32->bf16 -> [qkv] X@W^T+b (Q pre-scaled by 0.125*log2e; K row-major;
// V as [B,H,64,2048] with keys PERMUTED within each 64-block: k'=(k&15)*4+(k>>4))
// -> [attn] flash attention (128q blocks, wave=32q x 64keys for 2x K/V fragment
// reuse; K/V LDS-staged coalesced; fixed-max softmax; packed b64 P writes)
// -> [proj] O@Wo^T+bo -> fp32 d_out.
// LAW (r7/r8): MFMA fragments are lane-granular gathers -> always read them from
// LDS; keep all global accesses contiguous (staging loads / scatter stores only).

typedef unsigned short u16;
typedef __attribute__((ext_vector_type(8))) short short8;   // 8 bf16 (MFMA A/B frag)
typedef __attribute__((ext_vector_type(4))) float floatx4;  // MFMA C/D frag

__device__ __forceinline__ float bf2f(u16 x) {
  return __uint_as_float(((unsigned)x) << 16);
}
__device__ __forceinline__ u16 f2bf(float f) {
  unsigned x = __float_as_uint(f);
  return (u16)((x + 0x7fffu + ((x >> 16) & 1u)) >> 16);  // RNE
}
__device__ __forceinline__ ushort2 pk_bf16(float a, float b) {
  __hip_bfloat162 h2 = __float22bfloat162_rn(make_float2(a, b));  // v_cvt_pk_bf16_f32
  ushort2 u;
  __builtin_memcpy(&u, &h2, 4);
  return u;
}
#if __has_builtin(__builtin_amdgcn_exp2f)
#define EXP2(x) __builtin_amdgcn_exp2f(x)
#else
#define EXP2(x) exp2f(x)
#endif
__device__ __forceinline__ void gll16(const u16* g, u16* lds) {
  __builtin_amdgcn_global_load_lds((const __attribute__((address_space(1))) void*)g,
                                   (__attribute__((address_space(3))) void*)lds,
                                   16, 0, 0);
}
// Compiler reorder barrier + DS drain (doesn't touch vmcnt: global loads in flight)
#define DSFENCE() __asm__ volatile("s_waitcnt lgkmcnt(0)" ::: "memory")

// ---------------------------------------------------------------------------
// fp32 -> bf16 of all 11 inputs. 16388 blocks x 256 thr x 4 elem, exact cover.
// ---------------------------------------------------------------------------
__global__ __launch_bounds__(256) void cvt_kernel(
    const float* __restrict__ q, const float* __restrict__ k, const float* __restrict__ v,
    const float* __restrict__ wq, const float* __restrict__ wk,
    const float* __restrict__ wv, const float* __restrict__ wo,
    const float* __restrict__ bq, const float* __restrict__ bk,
    const float* __restrict__ bv, const float* __restrict__ bo,
    u16* __restrict__ ws) {
  const int i4 = (blockIdx.x * 256 + threadIdx.x) * 4;
  const float* src;
  u16* dst;
  int local;
  if (i4 < 4194304)        { src = q;  dst = ws;            local = i4; }
  else if (i4 < 8388608)   { src = k;  dst = ws + 4194304;  local = i4 - 4194304; }
  else if (i4 < 12582912)  { src = v;  dst = ws + 8388608;  local = i4 - 8388608; }
  else if (i4 < 13631488)  { src = wq; dst = ws + 12582912; local = i4 - 12582912; }
  else if (i4 < 14680064)  { src = wk; dst = ws + 13631488; local = i4 - 13631488; }
  else if (i4 < 15728640)  { src = wv; dst = ws + 14680064; local = i4 - 14680064; }
  else if (i4 < 16777216)  { src = wo; dst = ws + 15728640; local = i4 - 15728640; }
  else if (i4 < 16778240)  { src = bq; dst = ws + 16777216; local = i4 - 16777216; }
  else if (i4 < 16779264)  { src = bk; dst = ws + 16779264; local = i4 - 16778240; }
  else if (i4 < 16780288)  { src = bv; dst = ws + 16781312; local = i4 - 16779264; }
  else                     { src = bo; dst = ws + 16783360; local = i4 - 16780288; }
  const float4 f = *(const float4*)(src + local);
  ushort4 o;
  o.x = f2bf(f.x); o.y = f2bf(f.y); o.z = f2bf(f.z); o.w = f2bf(f.w);
  *(ushort4*)(dst + local) = o;
}

// ---------------------------------------------------------------------------
// GEMM tile (m97 structure): out[m][n] = (X[m][:].W[n][:] + bias[n]) * oscale
// 256 thr (2x2 waves of 64x64), tile 128x128, BK=32, gll16 width-16 staging.
// mode 0: bf16 row-major. mode 1: bf16 [b][h][dd][s'] (s' = key-permuted within
// 64-blocks: k'=(k&15)*4+(k>>4)). mode 2: fp32 row-major.
// ---------------------------------------------------------------------------
__device__ __forceinline__ void gemm_tile(
    const u16* __restrict__ X, const u16* __restrict__ W,
    const u16* __restrict__ bias, u16* __restrict__ out16, float* __restrict__ out32,
    int row0, int col0, int mode, float oscale, u16* As, u16* Bs) {
  const int tid = threadIdx.x;
  const int w = tid >> 6, l = tid & 63;
  const int lan = l & 15, quad = l >> 4;
  const int wm = w & 1, wn = w >> 1;

  floatx4 acc[4][4];
#pragma unroll
  for (int i = 0; i < 4; ++i)
#pragma unroll
    for (int j = 0; j < 4; ++j) acc[i][j] = (floatx4)0.0f;

  const int r0 = tid >> 2, kq0 = tid & 3;
  const int r1 = (tid + 256) >> 2;
  u16* aB0 = As + w * 512;
  u16* aB1 = As + 2048 + w * 512;
  u16* bB0 = Bs + w * 512;
  u16* bB1 = Bs + 2048 + w * 512;
  const u16* Xa0 = X + (size_t)(row0 + r0) * 1024 + kq0 * 8;
  const u16* Xa1 = X + (size_t)(row0 + r1) * 1024 + kq0 * 8;
  const u16* Wb0 = W + (size_t)(col0 + r0) * 1024 + kq0 * 8;
  const u16* Wb1 = W + (size_t)(col0 + r1) * 1024 + kq0 * 8;

  for (int kt = 0; kt < 32; ++kt) {
    gll16(Xa0 + kt * 32, aB0);
    gll16(Xa1 + kt * 32, aB1);
    gll16(Wb0 + kt * 32, bB0);
    gll16(Wb1 + kt * 32, bB1);
    __syncthreads();

    short8 af[4], bfr[4];
#pragma unroll
    for (int i = 0; i < 4; ++i)
      af[i] = *(const short8*)(As + (wm * 64 + i * 16 + lan) * 32 + quad * 8);
#pragma unroll
    for (int j = 0; j < 4; ++j)
      bfr[j] = *(const short8*)(Bs + (wn * 64 + j * 16 + lan) * 32 + quad * 8);
#pragma unroll
    for (int i = 0; i < 4; ++i)
#pragma unroll
      for (int j = 0; j < 4; ++j)
        acc[i][j] = __builtin_amdgcn_mfma_f32_16x16x32_bf16(af[i], bfr[j], acc[i][j], 0, 0, 0);
    __syncthreads();
  }

#pragma unroll
  for (int i = 0; i < 4; ++i) {
    const int mb = row0 + wm * 64 + i * 16 + quad * 4;
#pragma unroll
    for (int j = 0; j < 4; ++j) {
      const int n = col0 + wn * 64 + j * 16 + lan;
      const float bv = bf2f(bias[n]);
      if (mode == 0) {
#pragma unroll
        for (int r = 0; r < 4; ++r)
          out16[(size_t)(mb + r) * 1024 + n] = f2bf((acc[i][j][r] + bv) * oscale);
      } else if (mode == 1) {
        // V head-transposed + key-permuted: token s -> slot (s&~63)|((s&15)*4+((s>>4)&3))
        const int b = mb >> 11;
        const int h = n >> 6, dd = n & 63;
        u16* base = out16 + (size_t)((b * 16 + h) * 64 + dd) * 2048;
#pragma unroll
        for (int r = 0; r < 4; ++r) {
          const int s = (mb + r) & 2047;
          const int sp = (s & ~63) | ((s & 15) * 4 + ((s >> 4) & 3));
          base[sp] = f2bf(acc[i][j][r] + bv);
        }
      } else {
#pragma unroll
        for (int r = 0; r < 4; ++r)
          out32[(size_t)(mb + r) * 1024 + n] = acc[i][j][r] + bv;
      }
    }
  }
}

__global__ __launch_bounds__(256) void qkv_kernel(
    const u16* __restrict__ xq, const u16* __restrict__ xk, const u16* __restrict__ xv,
    const u16* __restrict__ Wq, const u16* __restrict__ Wk, const u16* __restrict__ Wv,
    const u16* __restrict__ bq, const u16* __restrict__ bk, const u16* __restrict__ bv,
    u16* __restrict__ Qo, u16* __restrict__ Ko, u16* __restrict__ Vto) {
  __shared__ __align__(16) u16 As[128 * 32];
  __shared__ __align__(16) u16 Bs[128 * 32];
  const int bx = blockIdx.x;           // 0..767
  const int tile_m = bx / 24;
  const int rem = bx - tile_m * 24;
  const int which = rem >> 3;          // 0=Q 1=K 2=V
  const int col0 = (rem & 7) * 128;
  const u16* X = which == 0 ? xq : (which == 1 ? xk : xv);
  const u16* W = which == 0 ? Wq : (which == 1 ? Wk : Wv);
  const u16* bias = which == 0 ? bq : (which == 1 ? bk : bv);
  u16* out = which == 0 ? Qo : (which == 1 ? Ko : Vto);
  const float C = 0.125f * 1.4426950408889634f;  // fold scale*log2e into Q
  gemm_tile(X, W, bias, out, nullptr, tile_m * 128, col0, which == 2 ? 1 : 0,
            which == 0 ? C : 1.0f, As, Bs);
}

__global__ __launch_bounds__(256) void proj_kernel(
    const u16* __restrict__ X, const u16* __restrict__ W,
    const u16* __restrict__ bias, float* __restrict__ out) {
  __shared__ __align__(16) u16 As[128 * 32];
  __shared__ __align__(16) u16 Bs[128 * 32];
  const int bx = blockIdx.x;  // 0..255
  gemm_tile(X, W, bias, nullptr, out, (bx >> 3) * 128, (bx & 7) * 128, 2, 1.0f, As, Bs);
}

// ---------------------------------------------------------------------------
// Flash attention v8 (r9 + 2x fragment reuse). grid (16 qtiles of 128, 32 bh),
// 256 thr, 4 waves; wave owns 32 q rows (mi=0,1) x all 64 keys of the tile.
// Every K/V fragment feeds TWO MFMAs (mi), halving LDS bytes per MFMA:
// per wave-kt: 32 MFMA vs reads 8(bkf)+8(vb)+4(pa) b128 + writes 4 b128 + 8 b64.
//  - K/V: coalesced LDS staging (stride 72), register-prefetched one tile ahead.
//  - Q: A-frags direct from global once (contiguous 64B rows -> coalesced).
//  - softmax: fixed-max (p=exp2(C*qk-16)), raw v_exp_f32 + packed bf16 cvt.
//  - P: ONE ushort4 (b64) write per row (key-permuted k'=lan*4+nj, matches V).
// LDS: Ks 9216 + Vs 9216 + Ps[128][72] 18432 = 36864 B; grid 512 -> 2 blocks/CU.
// ---------------------------------------------------------------------------
#define FIXMAX 16.0f
#define KPAD 72
__global__ __launch_bounds__(256, 2) void attn_kernel(
    const u16* __restrict__ Q, const u16* __restrict__ K,
    const u16* __restrict__ Vt, u16* __restrict__ O) {
  __shared__ __align__(16) u16 Ks[64 * KPAD];   // [key][dd]
  __shared__ __align__(16) u16 Vs[64 * KPAD];   // [dd][key']
  __shared__ __align__(16) u16 Ps[128 * KPAD];  // [q][key']
  const int tid = threadIdx.x;
  const int w = tid >> 6, l = tid & 63;
  const int lan = l & 15, quad = l >> 4;
  const int q0 = blockIdx.x * 128;
  const int bh = blockIdx.y;
  const int b = bh >> 4, h = bh & 15;
  const u16* Qg = Q + (size_t)(b * 2048 + q0) * 1024 + h * 64;
  const u16* Kg = K + (size_t)(b * 2048) * 1024 + h * 64;
  const u16* Vg = Vt + (size_t)((b * 16 + h) * 64) * 2048;

  // Q A-frags direct from global: rows w*32 + mi*16 + lan (contiguous 64B rows)
  short8 aq[2][2];
#pragma unroll
  for (int mi = 0; mi < 2; ++mi)
#pragma unroll
    for (int kk = 0; kk < 2; ++kk)
      aq[mi][kk] = *(const short8*)(Qg + (size_t)(w * 32 + mi * 16 + lan) * 1024 +
                                    kk * 32 + quad * 8);

  float lrun[2][4];
  floatx4 oacc[2][4];
#pragma unroll
  for (int mi = 0; mi < 2; ++mi) {
#pragma unroll
    for (int r = 0; r < 4; ++r) lrun[mi][r] = 0.f;
#pragma unroll
    for (int nd = 0; nd < 4; ++nd) oacc[mi][nd] = (floatx4)0.0f;
  }

  // staging maps: 64 rows x 8 chunks of 16B = 512 chunks, 2/thread (coalesced)
  const int rowA = tid >> 3, colq = (tid & 7) * 8;  // rows 0..31
  const int rowB = rowA + 32;                       // rows 32..63

  // prefetch tile 0 (K rows = keys; V rows = dd, cols already key-permuted)
  short8 k0 = *(const short8*)(Kg + (size_t)rowA * 1024 + colq);
  short8 k1 = *(const short8*)(Kg + (size_t)rowB * 1024 + colq);
  short8 v0 = *(const short8*)(Vg + (size_t)rowA * 2048 + colq);
  short8 v1 = *(const short8*)(Vg + (size_t)rowB * 2048 + colq);

  for (int kt = 0; kt < 32; ++kt) {
    __syncthreads();  // prior iteration's Ks/Vs reads complete
    *(short8*)(Ks + rowA * KPAD + colq) = k0;
    *(short8*)(Ks + rowB * KPAD + colq) = k1;
    *(short8*)(Vs + rowA * KPAD + colq) = v0;
    *(short8*)(Vs + rowB * KPAD + colq) = v1;
    __syncthreads();  // staging visible

    // prefetch next tile (in flight across this iteration's compute)
    const int kn = kt < 31 ? kt + 1 : 31;
    k0 = *(const short8*)(Kg + (size_t)(kn * 64 + rowA) * 1024 + colq);
    k1 = *(const short8*)(Kg + (size_t)(kn * 64 + rowB) * 1024 + colq);
    v0 = *(const short8*)(Vg + (size_t)rowA * 2048 + kn * 64 + colq);
    v1 = *(const short8*)(Vg + (size_t)rowB * 2048 + kn * 64 + colq);

    // S = Q K^T : 32q x 64keys per wave. B-frag: K[n=key][k=dd], reused by both mi
    short8 bkf[4][2];
#pragma unroll
    for (int nj = 0; nj < 4; ++nj)
#pragma unroll
      for (int kk = 0; kk < 2; ++kk)
        bkf[nj][kk] = *(const short8*)(Ks + (nj * 16 + lan) * KPAD + kk * 32 + quad * 8);

    floatx4 sacc[2][4];
#pragma unroll
    for (int mi = 0; mi < 2; ++mi)
#pragma unroll
      for (int nj = 0; nj < 4; ++nj) sacc[mi][nj] = (floatx4)(-FIXMAX);
#pragma unroll
    for (int kk = 0; kk < 2; ++kk)
#pragma unroll
      for (int mi = 0; mi < 2; ++mi)
#pragma unroll
        for (int nj = 0; nj < 4; ++nj)
          sacc[mi][nj] =
              __builtin_amdgcn_mfma_f32_16x16x32_bf16(aq[mi][kk], bkf[nj][kk], sacc[mi][nj], 0, 0, 0);

    // fixed-max softmax; lane holds cols lan+{0,16,32,48} -> packed slot lan*4+nj
#pragma unroll
    for (int mi = 0; mi < 2; ++mi)
#pragma unroll
      for (int r = 0; r < 4; ++r) {
        const float p0 = EXP2(sacc[mi][0][r]), p1 = EXP2(sacc[mi][1][r]);
        const float p2 = EXP2(sacc[mi][2][r]), p3 = EXP2(sacc[mi][3][r]);
        lrun[mi][r] += (p0 + p1) + (p2 + p3);
        const ushort2 a01 = pk_bf16(p0, p1);
        const ushort2 a23 = pk_bf16(p2, p3);
        ushort4 pp;
        pp.x = a01.x; pp.y = a01.y; pp.z = a23.x; pp.w = a23.y;
        const int qrow = w * 32 + mi * 16 + quad * 4 + r;
        *(ushort4*)(Ps + qrow * KPAD + lan * 4) = pp;  // ONE b64 write
      }
    DSFENCE();  // P writes ordered/visible before same-wave A-frag reads

    // O += P V : A-frag P[m=q][k'], B-frag V[n=dd][k'] (same permutation, reused by mi)
    short8 pa[2][2];
#pragma unroll
    for (int mi = 0; mi < 2; ++mi)
#pragma unroll
      for (int kk = 0; kk < 2; ++kk)
        pa[mi][kk] = *(const short8*)(Ps + (w * 32 + mi * 16 + lan) * KPAD + kk * 32 + quad * 8);
    short8 vb[4][2];
#pragma unroll
    for (int nd = 0; nd < 4; ++nd)
#pragma unroll
      for (int kk = 0; kk < 2; ++kk)
        vb[nd][kk] = *(const short8*)(Vs + (nd * 16 + lan) * KPAD + kk * 32 + quad * 8);
#pragma unroll
    for (int kk = 0; kk < 2; ++kk)
#pragma unroll
      for (int mi = 0; mi < 2; ++mi)
#pragma unroll
        for (int nd = 0; nd < 4; ++nd)
          oacc[mi][nd] =
              __builtin_amdgcn_mfma_f32_16x16x32_bf16(pa[mi][kk], vb[nd][kk], oacc[mi][nd], 0, 0, 0);
  }

  // reduce lane-distributed lrun across the 16-lane group, store O
#pragma unroll
  for (int mi = 0; mi < 2; ++mi)
#pragma unroll
    for (int r = 0; r < 4; ++r) {
      float ls = lrun[mi][r];
#pragma unroll
      for (int d = 1; d < 16; d <<= 1) ls += __shfl_xor(ls, d);
      const float inv = 1.0f / ls;
      const int mg = b * 2048 + q0 + w * 32 + mi * 16 + quad * 4 + r;
#pragma unroll
      for (int nd = 0; nd < 4; ++nd) {
        const int col = h * 64 + nd * 16 + lan;
        O[(size_t)mg * 1024 + col] = f2bf(oacc[mi][nd][r] * inv);
      }
    }
}

extern "C" void kernel_launch(void* const* d_in, const int* in_sizes, int n_in,
                              void* d_out, int out_size, void* d_ws, size_t ws_size,
                              hipStream_t stream) {
  const float* query = (const float*)d_in[0];
  const float* key_ = (const float*)d_in[1];
  const float* value = (const float*)d_in[2];
  const float* Wq = (const float*)d_in[3];
  const float* bq = (const float*)d_in[4];
  const float* Wk = (const float*)d_in[5];
  const float* bk = (const float*)d_in[6];
  const float* Wv = (const float*)d_in[7];
  const float* bv = (const float*)d_in[8];
  const float* Wo = (const float*)d_in[9];
  const float* bo = (const float*)d_in[10];
  float* out = (float*)d_out;

  u16* ws = (u16*)d_ws;
  u16* Xq = ws;
  u16* Xk = ws + 4194304;
  u16* Xv = ws + 8388608;
  u16* cWq = ws + 12582912;
  u16* cWk = ws + 13631488;
  u16* cWv = ws + 14680064;
  u16* cWo = ws + 15728640;
  u16* cbq = ws + 16777216;
  u16* cbk = ws + 16779264;
  u16* cbv = ws + 16781312;
  u16* cbo = ws + 16783360;
  u16* Qw = ws + 17301504;
  u16* Kw = ws + 21495808;
  u16* Vtw = ws + 25690112;
  u16* Ow = ws + 29884416;

  cvt_kernel<<<16388, 256, 0, stream>>>(query, key_, value, Wq, Wk, Wv, Wo,
                                        bq, bk, bv, bo, ws);
  qkv_kernel<<<768, 256, 0, stream>>>(Xq, Xk, Xv, cWq, cWk, cWv, cbq, cbk, cbv,
                                      Qw, Kw, Vtw);
  attn_kernel<<<dim3(16, 32), 256, 0, stream>>>(Qw, Kw, Vtw, Ow);
  proj_kernel<<<256, 256, 0, stream>>>(Ow, cWo, cbo, out);
}